// Round 11
// baseline (385.530 us; speedup 1.0000x reference)
//
#include <hip/hip_runtime.h>
#include <hip/hip_bf16.h>

// ---------------------------------------------------------------------------
// GCN 2-layer forward on MI355X.
// Round 11: (1) edge-split SpMMs: 2 waves per dst node (stride-2 edges,
// LDS combine) -> 2x waves, 2x loads in flight (R10 evidence: 16-deep batch
// = 8-deep, L3-warm = L3-cold -> per-wave MLP-limited, not LLC-BW).
// (2) shuffle-based scans in scanB/passC/passD (20-32 barriers -> 2).
// ---------------------------------------------------------------------------

#define NPP_SHIFT 9
#define NPP 512
#define MAXP 256
#define NB 512

typedef __attribute__((ext_vector_type(8))) short frag8;
typedef __attribute__((ext_vector_type(4))) float f32x4;

__device__ inline int wave_incl_scan(int v) {
    int lane = threadIdx.x & 63;
#pragma unroll
    for (int off = 1; off < 64; off <<= 1) {
        int t = __shfl_up(v, off);
        if (lane >= off) v += t;
    }
    return v;
}

// ---- Pass A: per-block histograms of src-partition and dst-partition ----
__launch_bounds__(256)
__global__ void passA_count(const int* __restrict__ src, const int* __restrict__ dst,
                            int E, int P, int* __restrict__ counts_src,
                            int* __restrict__ counts_dst) {
    __shared__ int h1[MAXP], h2[MAXP];
    int tid = threadIdx.x;
    for (int i = tid; i < P; i += 256) { h1[i] = 0; h2[i] = 0; }
    __syncthreads();
    int per_block = (E + NB - 1) / NB;
    int e0 = blockIdx.x * per_block;
    int e1 = min(e0 + per_block, E);
    for (int e = e0 + tid; e < e1; e += 256) {
        atomicAdd(&h1[src[e] >> NPP_SHIFT], 1);
        atomicAdd(&h2[dst[e] >> NPP_SHIFT], 1);
    }
    __syncthreads();
    for (int i = tid; i < P; i += 256) {
        counts_src[(size_t)blockIdx.x * P + i] = h1[i];
        counts_dst[(size_t)blockIdx.x * P + i] = h2[i];
    }
}

// ---- Pass B: exclusive scan across NB=512 blocks per (stream, partition) --
// 512 threads, shuffle scan + 2 barriers.
__launch_bounds__(512)
__global__ void scanB(const int* __restrict__ counts, int* __restrict__ offs,
                      int* __restrict__ ptot, int P) {
    __shared__ int wsum[8];
    int tid = threadIdx.x;
    int wave = tid >> 6;
    int p = blockIdx.x % P;
    int st = blockIdx.x / P;
    const int* c = counts + (size_t)st * NB * P;
    int v = c[(size_t)tid * P + p];
    int incl = wave_incl_scan(v);
    if ((tid & 63) == 63) wsum[wave] = incl;
    __syncthreads();
    if (tid == 0) {
        int a = 0;
#pragma unroll
        for (int i = 0; i < 8; ++i) { int t = wsum[i]; wsum[i] = a; a += t; }
        ptot[st * P + p] = a;
    }
    __syncthreads();
    offs[(size_t)st * NB * P + (size_t)tid * P + p] = incl - v + wsum[wave];
}

// ---- Pass C: scatter into partition-bucketed buffers (LDS cursors) ------
__launch_bounds__(256)
__global__ void passC_scatter(const int* __restrict__ src, const int* __restrict__ dst,
                              int E, int P, const int* __restrict__ offs,
                              const int* __restrict__ ptot, int* __restrict__ pbase,
                              int* __restrict__ ebuf_src, int2* __restrict__ ebuf_dst) {
    __shared__ int cur1[MAXP], cur2[MAXP], wsum[4];
    int tid = threadIdx.x;
    int wave = tid >> 6;
    // stream 0 scan of ptot[0..P)
    int v = (tid < P) ? ptot[tid] : 0;
    int incl = wave_incl_scan(v);
    if ((tid & 63) == 63) wsum[wave] = incl;
    __syncthreads();
    if (tid == 0) {
        int a = 0;
#pragma unroll
        for (int i = 0; i < 4; ++i) { int t = wsum[i]; wsum[i] = a; a += t; }
    }
    __syncthreads();
    int base0 = incl - v + wsum[wave];
    if (tid < P) {
        cur1[tid] = base0 + offs[(size_t)blockIdx.x * P + tid];
        if (blockIdx.x == 0) pbase[tid] = base0;
    }
    __syncthreads();
    // stream 1 scan
    v = (tid < P) ? ptot[P + tid] : 0;
    incl = wave_incl_scan(v);
    if ((tid & 63) == 63) wsum[wave] = incl;
    __syncthreads();
    if (tid == 0) {
        int a = 0;
#pragma unroll
        for (int i = 0; i < 4; ++i) { int t = wsum[i]; wsum[i] = a; a += t; }
    }
    __syncthreads();
    int base1 = incl - v + wsum[wave];
    if (tid < P) {
        cur2[tid] = base1 + offs[(size_t)NB * P + (size_t)blockIdx.x * P + tid];
        if (blockIdx.x == 0) pbase[P + tid] = base1;
    }
    __syncthreads();
    int per_block = (E + NB - 1) / NB;
    int e0 = blockIdx.x * per_block;
    int e1 = min(e0 + per_block, E);
    for (int e = e0 + tid; e < e1; e += 256) {
        int s = src[e];
        int d = dst[e];
        int pos1 = atomicAdd(&cur1[s >> NPP_SHIFT], 1);
        ebuf_src[pos1] = s;
        int pos2 = atomicAdd(&cur2[d >> NPP_SHIFT], 1);
        ebuf_dst[pos2] = make_int2(d, s);
    }
}

// ---- Pass D: per-partition degree/norm/row_start/csr build --------------
__launch_bounds__(512)
__global__ void passD_build(const int* __restrict__ ebuf_src, const int2* __restrict__ ebuf_dst,
                            const int* __restrict__ ptot, const int* __restrict__ pbase,
                            float* __restrict__ norm_src, int* __restrict__ row_start,
                            int* __restrict__ csr_src, int N, int E, int P) {
    __shared__ int hs[NPP], hd[NPP], wsum[8];
    int tid = threadIdx.x;
    int wave = tid >> 6;
    int p = blockIdx.x;
    int node_lo = p << NPP_SHIFT;
    int nl = min(NPP, N - node_lo);
    hs[tid] = 0;
    hd[tid] = 0;
    __syncthreads();
    int nsrc = ptot[p];
    int base_s = pbase[p];
    for (int i = tid; i < nsrc; i += 512)
        atomicAdd(&hs[ebuf_src[base_s + i] - node_lo], 1);
    int ndst = ptot[P + p];
    int base_d = pbase[P + p];
    for (int i = tid; i < ndst; i += 512)
        atomicAdd(&hd[ebuf_dst[base_d + i].x - node_lo], 1);
    __syncthreads();
    if (tid < nl) norm_src[node_lo + tid] = rsqrtf((float)max(hs[tid], 1));
    int myh = hd[tid];
    int incl = wave_incl_scan(myh);
    if ((tid & 63) == 63) wsum[wave] = incl;
    __syncthreads();
    if (tid == 0) {
        int a = 0;
#pragma unroll
        for (int i = 0; i < 8; ++i) { int t = wsum[i]; wsum[i] = a; a += t; }
    }
    __syncthreads();
    int row0 = base_d + incl - myh + wsum[wave];
    if (tid < nl) row_start[node_lo + tid] = row0;
    if (p == P - 1 && tid == 0) row_start[N] = E;
    __syncthreads();
    hd[tid] = row0;  // reuse as cursor
    __syncthreads();
    for (int i = tid; i < ndst; i += 512) {
        int2 r = ebuf_dst[base_d + i];
        int pos = atomicAdd(&hd[r.x - node_lo], 1);
        csr_src[pos] = r.y;
    }
}

// ---- MFMA GEMM: out[n x COLS](bf16) = A[n x 128] @ W[128 x COLS] --------
template <int COLS, bool BF16IN>
__launch_bounds__(256)
__global__ void gemm_mfma(const void* __restrict__ xin, const float* __restrict__ w,
                          const float* __restrict__ norm,
                          __hip_bfloat16* __restrict__ out, int n) {
    constexpr int NT = COLS / 16;
    __shared__ short wlds[4 * NT * 64 * 8];
    const int tid = threadIdx.x;
    for (int i = tid; i < 128 * COLS / 4; i += 256) {
        int k = (i * 4) / COLS;
        int n0 = (i * 4) % COLS;
        float4 wv = reinterpret_cast<const float4*>(w)[i];
        int c = k >> 5, q = (k >> 3) & 3, j = k & 7;
        float vals[4] = {wv.x, wv.y, wv.z, wv.w};
#pragma unroll
        for (int u = 0; u < 4; ++u) {
            int nn = n0 + u;
            int t = nn >> 4;
            int ln = (q << 4) | (nn & 15);
            union { __hip_bfloat16 b; short s; } cv;
            cv.b = __float2bfloat16(vals[u]);
            wlds[(((c * NT + t) << 6) | ln) * 8 + j] = cv.s;
        }
    }
    __syncthreads();

    const int lane = tid & 63;
    const int wid = tid >> 6;
    const int m = lane & 15;
    const int q = lane >> 4;
    const int ntiles = (n + 15) >> 4;
    const frag8* wfr = reinterpret_cast<const frag8*>(wlds);

    for (int wt = blockIdx.x * 4 + wid; wt < ntiles; wt += gridDim.x * 4) {
        const int row = (wt << 4) + m;
        frag8 af[4];
        if (row < n) {
            if constexpr (BF16IN) {
                const frag8* xp = reinterpret_cast<const frag8*>(
                    (const __hip_bfloat16*)xin + (size_t)row * 128);
#pragma unroll
                for (int c = 0; c < 4; ++c) af[c] = xp[c * 4 + q];
            } else {
                const float* xp = (const float*)xin + (size_t)row * 128;
                float nm = norm[row];
#pragma unroll
                for (int c = 0; c < 4; ++c) {
                    int base = c * 32 + q * 8;
                    float4 v0 = *reinterpret_cast<const float4*>(xp + base);
                    float4 v1 = *reinterpret_cast<const float4*>(xp + base + 4);
                    union { frag8 f; short s[8]; } a;
                    union { __hip_bfloat16 b; short s; } cv;
                    cv.b = __float2bfloat16(v0.x * nm); a.s[0] = cv.s;
                    cv.b = __float2bfloat16(v0.y * nm); a.s[1] = cv.s;
                    cv.b = __float2bfloat16(v0.z * nm); a.s[2] = cv.s;
                    cv.b = __float2bfloat16(v0.w * nm); a.s[3] = cv.s;
                    cv.b = __float2bfloat16(v1.x * nm); a.s[4] = cv.s;
                    cv.b = __float2bfloat16(v1.y * nm); a.s[5] = cv.s;
                    cv.b = __float2bfloat16(v1.z * nm); a.s[6] = cv.s;
                    cv.b = __float2bfloat16(v1.w * nm); a.s[7] = cv.s;
                    af[c] = a.f;
                }
            }
        } else {
#pragma unroll
            for (int c = 0; c < 4; ++c) af[c] = frag8{0, 0, 0, 0, 0, 0, 0, 0};
        }
        f32x4 acc[NT] = {};
#pragma unroll
        for (int c = 0; c < 4; ++c)
#pragma unroll
            for (int t = 0; t < NT; ++t)
                acc[t] = __builtin_amdgcn_mfma_f32_16x16x32_bf16(
                    af[c], wfr[(c * NT + t) * 64 + lane], acc[t], 0, 0, 0);
#pragma unroll
        for (int r = 0; r < 4; ++r) {
            int grow = (wt << 4) + q * 4 + r;
            if (grow < n) {
#pragma unroll
                for (int t = 0; t < NT; ++t)
                    out[(size_t)grow * COLS + t * 16 + m] = __float2bfloat16(acc[t][r]);
            }
        }
    }
}

// ---- SpMM layer 1: 2 waves per dst node (stride-2 edges), LDS combine ---
__launch_bounds__(256)
__global__ void spmm1_kernel(const __hip_bfloat16* __restrict__ h,
                             const int* __restrict__ row_start,
                             const int* __restrict__ csr_src,
                             const float* __restrict__ b1,
                             const float* __restrict__ norm_src,
                             uint* __restrict__ out, int n) {
    int tid = threadIdx.x;
    int wave_g = (blockIdx.x * 256 + tid) >> 6;
    int gw = wave_g >> 1;
    int sub = wave_g & 1;
    int lane = tid & 63;
    int lwave = tid >> 6;
    __shared__ float2 sbuf[4][64];
    float2 acc = {0.f, 0.f};
    int e0 = 0, e1 = 0;
    bool active = gw < n;
    if (active) {
        e0 = row_start[gw];
        e1 = row_start[gw + 1];
        const uint* hp = reinterpret_cast<const uint*>(h);
        int e = e0 + sub;
        for (; e + 14 < e1; e += 16) {
            uint v[8];
#pragma unroll
            for (int j = 0; j < 8; ++j)
                v[j] = hp[(size_t)csr_src[e + 2 * j] * 64 + lane];
#pragma unroll
            for (int j = 0; j < 8; ++j) {
                acc.x += __uint_as_float(v[j] << 16);
                acc.y += __uint_as_float(v[j] & 0xffff0000u);
            }
        }
        if (e + 6 < e1) {
            uint v[4];
#pragma unroll
            for (int j = 0; j < 4; ++j)
                v[j] = hp[(size_t)csr_src[e + 2 * j] * 64 + lane];
#pragma unroll
            for (int j = 0; j < 4; ++j) {
                acc.x += __uint_as_float(v[j] << 16);
                acc.y += __uint_as_float(v[j] & 0xffff0000u);
            }
            e += 8;
        }
        for (; e < e1; e += 2) {
            uint v0 = hp[(size_t)csr_src[e] * 64 + lane];
            acc.x += __uint_as_float(v0 << 16);
            acc.y += __uint_as_float(v0 & 0xffff0000u);
        }
    }
    sbuf[lwave][lane] = acc;
    __syncthreads();
    if (active && sub == 0) {
        float2 pp = sbuf[lwave ^ 1][lane];
        acc.x += pp.x;
        acc.y += pp.y;
        float nd = rsqrtf((float)max(e1 - e0, 1));
        float ns = norm_src[gw];
        float2 bb = reinterpret_cast<const float2*>(b1)[lane];
        float ox = fmaxf(fmaf(acc.x, nd, bb.x), 0.f) * ns;
        float oy = fmaxf(fmaf(acc.y, nd, bb.y), 0.f) * ns;
        union { __hip_bfloat16 b; ushort s; } cx, cy;
        cx.b = __float2bfloat16(ox);
        cy.b = __float2bfloat16(oy);
        out[(size_t)gw * 64 + lane] = (uint)cx.s | ((uint)cy.s << 16);
    }
}

// ---- SpMM layer 2: 2 waves per dst node, LDS combine; emits bf16 y ------
__launch_bounds__(256)
__global__ void spmm2_kernel(const __hip_bfloat16* __restrict__ h,
                             const int* __restrict__ row_start,
                             const int* __restrict__ csr_src,
                             const float* __restrict__ b2, ushort* __restrict__ y, int n) {
    int tid = threadIdx.x;
    int wave_g = (blockIdx.x * 256 + tid) >> 6;
    int gw = wave_g >> 1;
    int sub = wave_g & 1;
    int lane = tid & 63;
    int lwave = tid >> 6;
    __shared__ float sbuf[4][64];
    float acc = 0.f;
    int e0 = 0, e1 = 0;
    bool active = gw < n;
    if (active) {
        e0 = row_start[gw];
        e1 = row_start[gw + 1];
        const ushort* hp = reinterpret_cast<const ushort*>(h);
        int e = e0 + sub;
        for (; e + 14 < e1; e += 16) {
            uint v[8];
#pragma unroll
            for (int j = 0; j < 8; ++j)
                v[j] = hp[(size_t)csr_src[e + 2 * j] * 64 + lane];
#pragma unroll
            for (int j = 0; j < 8; ++j) acc += __uint_as_float(v[j] << 16);
        }
        if (e + 6 < e1) {
            uint v[4];
#pragma unroll
            for (int j = 0; j < 4; ++j)
                v[j] = hp[(size_t)csr_src[e + 2 * j] * 64 + lane];
#pragma unroll
            for (int j = 0; j < 4; ++j) acc += __uint_as_float(v[j] << 16);
            e += 8;
        }
        for (; e < e1; e += 2)
            acc += __uint_as_float((uint)hp[(size_t)csr_src[e] * 64 + lane] << 16);
    }
    sbuf[lwave][lane] = acc;
    __syncthreads();
    if (active && sub == 0) {
        acc += sbuf[lwave ^ 1][lane];
        float nd = rsqrtf((float)max(e1 - e0, 1));
        float val = fmaxf(fmaf(acc, nd, b2[lane]), 0.f);
        union { __hip_bfloat16 b; ushort s; } cv;
        cv.b = __float2bfloat16(val);
        y[(size_t)gw * 64 + lane] = cv.s;
    }
}

// ---- Fused pooling: one block per graph, binary-search bounds, divide ---
__launch_bounds__(256)
__global__ void pool_kernel(const ushort* __restrict__ y, const int* __restrict__ gids,
                            float* __restrict__ out, int n) {
    int g = blockIdx.x;
    int lo = 0, hi = n;
    while (lo < hi) {
        int mid = (lo + hi) >> 1;
        if (gids[mid] < g) lo = mid + 1; else hi = mid;
    }
    int s = lo;
    hi = n;
    while (lo < hi) {
        int mid = (lo + hi) >> 1;
        if (gids[mid] < g + 1) lo = mid + 1; else hi = mid;
    }
    int e = lo;
    int lane = threadIdx.x & 63;
    int wave = threadIdx.x >> 6;
    float acc = 0.f;
    int i = s + wave;
    for (; i + 12 < e; i += 16) {
        uint u0 = y[(size_t)(i + 0) * 64 + lane];
        uint u1 = y[(size_t)(i + 4) * 64 + lane];
        uint u2 = y[(size_t)(i + 8) * 64 + lane];
        uint u3 = y[(size_t)(i + 12) * 64 + lane];
        acc += __uint_as_float(u0 << 16) + __uint_as_float(u1 << 16) +
               __uint_as_float(u2 << 16) + __uint_as_float(u3 << 16);
    }
    for (; i < e; i += 4)
        acc += __uint_as_float((uint)y[(size_t)i * 64 + lane] << 16);
    __shared__ float sbuf[4][64];
    sbuf[wave][lane] = acc;
    __syncthreads();
    if (wave == 0) {
        float v = sbuf[0][lane] + sbuf[1][lane] + sbuf[2][lane] + sbuf[3][lane];
        out[(size_t)g * 64 + lane] = v / fmaxf((float)(e - s), 1.f);
    }
}

extern "C" void kernel_launch(void* const* d_in, const int* in_sizes, int n_in,
                              void* d_out, int out_size, void* d_ws, size_t ws_size,
                              hipStream_t stream) {
    const float* features = (const float*)d_in[0];
    const float* W1 = (const float*)d_in[1];
    const float* b1 = (const float*)d_in[2];
    const float* W2 = (const float*)d_in[3];
    const float* b2 = (const float*)d_in[4];
    const int* src = (const int*)d_in[5];
    const int* dst = (const int*)d_in[6];
    const int* gids = (const int*)d_in[7];
    const int N = in_sizes[7];
    const int E = in_sizes[5];
    const int G = out_size / 64;
    float* out = (float*)d_out;
    const int P = (N + NPP - 1) >> NPP_SHIFT;

    char* ws = (char*)d_ws;
    size_t off = 0;
    auto alloc = [&](size_t bytes) -> void* {
        void* p = ws + off;
        off = (off + bytes + 255) & ~(size_t)255;
        return p;
    };
    int* counts = (int*)alloc((size_t)2 * NB * P * 4);
    int* offs = (int*)alloc((size_t)2 * NB * P * 4);
    int* ptot = (int*)alloc((size_t)2 * P * 4);
    int* pbase = (int*)alloc((size_t)2 * P * 4);
    int* ebuf_src = (int*)alloc((size_t)E * 4);
    int2* ebuf_dst = (int2*)alloc((size_t)E * 8);
    float* norm_src = (float*)alloc((size_t)N * 4);
    int* row_start = (int*)alloc((size_t)(N + 1) * 4);
    int* csr_src = (int*)alloc((size_t)E * 4);
    __hip_bfloat16* h1 = (__hip_bfloat16*)alloc((size_t)N * 128 * 2);   // reused as h2
    __hip_bfloat16* x2n = (__hip_bfloat16*)alloc((size_t)N * 128 * 2);  // bf16, pre-normed
    ushort* y = (ushort*)alloc((size_t)N * 64 * 2);                     // bf16
    __hip_bfloat16* h2 = h1;  // h1 dead after spmm1

    // --- atomic-free graph build ---
    passA_count<<<NB, 256, 0, stream>>>(src, dst, E, P, counts, counts + (size_t)NB * P);
    scanB<<<2 * P, 512, 0, stream>>>(counts, offs, ptot, P);
    passC_scatter<<<NB, 256, 0, stream>>>(src, dst, E, P, offs, ptot, pbase,
                                          ebuf_src, ebuf_dst);
    passD_build<<<P, 512, 0, stream>>>(ebuf_src, ebuf_dst, ptot, pbase, norm_src, row_start,
                                       csr_src, N, E, P);

    // Layer 1: h1 = (features * norm_src) @ W1   (bf16 MFMA)
    gemm_mfma<128, false><<<768, 256, 0, stream>>>(features, W1, norm_src, h1, N);
    int spmm_blocks = (2 * N + 3) / 4;  // 2 waves per node, 4 waves per block
    spmm1_kernel<<<spmm_blocks, 256, 0, stream>>>(h1, row_start, csr_src, b1, norm_src,
                                                  (uint*)x2n, N);
    // Layer 2: h2 = x2n @ W2   (x2n already includes norm_src)
    gemm_mfma<64, true><<<768, 256, 0, stream>>>(x2n, W2, nullptr, h2, N);
    spmm2_kernel<<<spmm_blocks, 256, 0, stream>>>(h2, row_start, csr_src, b2, y, N);
    // Per-graph mean (one block per graph; sorted gids)
    pool_kernel<<<G, 256, 0, stream>>>(y, gids, out, N);
}

// Round 12
// 337.647 us; speedup vs baseline: 1.1418x; 1.1418x over previous
//
#include <hip/hip_runtime.h>
#include <hip/hip_bf16.h>

// ---------------------------------------------------------------------------
// GCN 2-layer forward on MI355X.
// Round 12: revert R11's edge-split (regressed 332->386: halved per-wave
// batch depth, added barriers). New spmm structure: pair-of-rows gathers --
// lane (h, r): uint2/uint load covers 2 rows per instruction = 8 lines
// (spmm1), 8-deep batch = 64 lines/wave in flight (2x R10). Cross-half
// combine via __shfl_xor(32), no LDS. 1 wave/node.
// ---------------------------------------------------------------------------

#define NPP_SHIFT 9
#define NPP 512
#define MAXP 256
#define NB 512

typedef __attribute__((ext_vector_type(8))) short frag8;
typedef __attribute__((ext_vector_type(4))) float f32x4;

__device__ inline int wave_incl_scan(int v) {
    int lane = threadIdx.x & 63;
#pragma unroll
    for (int off = 1; off < 64; off <<= 1) {
        int t = __shfl_up(v, off);
        if (lane >= off) v += t;
    }
    return v;
}

// ---- Pass A: per-block histograms of src-partition and dst-partition ----
__launch_bounds__(256)
__global__ void passA_count(const int* __restrict__ src, const int* __restrict__ dst,
                            int E, int P, int* __restrict__ counts_src,
                            int* __restrict__ counts_dst) {
    __shared__ int h1[MAXP], h2[MAXP];
    int tid = threadIdx.x;
    for (int i = tid; i < P; i += 256) { h1[i] = 0; h2[i] = 0; }
    __syncthreads();
    int per_block = (E + NB - 1) / NB;
    int e0 = blockIdx.x * per_block;
    int e1 = min(e0 + per_block, E);
    for (int e = e0 + tid; e < e1; e += 256) {
        atomicAdd(&h1[src[e] >> NPP_SHIFT], 1);
        atomicAdd(&h2[dst[e] >> NPP_SHIFT], 1);
    }
    __syncthreads();
    for (int i = tid; i < P; i += 256) {
        counts_src[(size_t)blockIdx.x * P + i] = h1[i];
        counts_dst[(size_t)blockIdx.x * P + i] = h2[i];
    }
}

// ---- Pass B: exclusive scan across NB=512 blocks per (stream, partition) --
__launch_bounds__(512)
__global__ void scanB(const int* __restrict__ counts, int* __restrict__ offs,
                      int* __restrict__ ptot, int P) {
    __shared__ int wsum[8];
    int tid = threadIdx.x;
    int wave = tid >> 6;
    int p = blockIdx.x % P;
    int st = blockIdx.x / P;
    const int* c = counts + (size_t)st * NB * P;
    int v = c[(size_t)tid * P + p];
    int incl = wave_incl_scan(v);
    if ((tid & 63) == 63) wsum[wave] = incl;
    __syncthreads();
    if (tid == 0) {
        int a = 0;
#pragma unroll
        for (int i = 0; i < 8; ++i) { int t = wsum[i]; wsum[i] = a; a += t; }
        ptot[st * P + p] = a;
    }
    __syncthreads();
    offs[(size_t)st * NB * P + (size_t)tid * P + p] = incl - v + wsum[wave];
}

// ---- Pass C: scatter into partition-bucketed buffers (LDS cursors) ------
__launch_bounds__(256)
__global__ void passC_scatter(const int* __restrict__ src, const int* __restrict__ dst,
                              int E, int P, const int* __restrict__ offs,
                              const int* __restrict__ ptot, int* __restrict__ pbase,
                              int* __restrict__ ebuf_src, int2* __restrict__ ebuf_dst) {
    __shared__ int cur1[MAXP], cur2[MAXP], wsum[4];
    int tid = threadIdx.x;
    int wave = tid >> 6;
    int v = (tid < P) ? ptot[tid] : 0;
    int incl = wave_incl_scan(v);
    if ((tid & 63) == 63) wsum[wave] = incl;
    __syncthreads();
    if (tid == 0) {
        int a = 0;
#pragma unroll
        for (int i = 0; i < 4; ++i) { int t = wsum[i]; wsum[i] = a; a += t; }
    }
    __syncthreads();
    int base0 = incl - v + wsum[wave];
    if (tid < P) {
        cur1[tid] = base0 + offs[(size_t)blockIdx.x * P + tid];
        if (blockIdx.x == 0) pbase[tid] = base0;
    }
    __syncthreads();
    v = (tid < P) ? ptot[P + tid] : 0;
    incl = wave_incl_scan(v);
    if ((tid & 63) == 63) wsum[wave] = incl;
    __syncthreads();
    if (tid == 0) {
        int a = 0;
#pragma unroll
        for (int i = 0; i < 4; ++i) { int t = wsum[i]; wsum[i] = a; a += t; }
    }
    __syncthreads();
    int base1 = incl - v + wsum[wave];
    if (tid < P) {
        cur2[tid] = base1 + offs[(size_t)NB * P + (size_t)blockIdx.x * P + tid];
        if (blockIdx.x == 0) pbase[P + tid] = base1;
    }
    __syncthreads();
    int per_block = (E + NB - 1) / NB;
    int e0 = blockIdx.x * per_block;
    int e1 = min(e0 + per_block, E);
    for (int e = e0 + tid; e < e1; e += 256) {
        int s = src[e];
        int d = dst[e];
        int pos1 = atomicAdd(&cur1[s >> NPP_SHIFT], 1);
        ebuf_src[pos1] = s;
        int pos2 = atomicAdd(&cur2[d >> NPP_SHIFT], 1);
        ebuf_dst[pos2] = make_int2(d, s);
    }
}

// ---- Pass D: per-partition degree/norm/row_start/csr build --------------
__launch_bounds__(512)
__global__ void passD_build(const int* __restrict__ ebuf_src, const int2* __restrict__ ebuf_dst,
                            const int* __restrict__ ptot, const int* __restrict__ pbase,
                            float* __restrict__ norm_src, int* __restrict__ row_start,
                            int* __restrict__ csr_src, int N, int E, int P) {
    __shared__ int hs[NPP], hd[NPP], wsum[8];
    int tid = threadIdx.x;
    int wave = tid >> 6;
    int p = blockIdx.x;
    int node_lo = p << NPP_SHIFT;
    int nl = min(NPP, N - node_lo);
    hs[tid] = 0;
    hd[tid] = 0;
    __syncthreads();
    int nsrc = ptot[p];
    int base_s = pbase[p];
    for (int i = tid; i < nsrc; i += 512)
        atomicAdd(&hs[ebuf_src[base_s + i] - node_lo], 1);
    int ndst = ptot[P + p];
    int base_d = pbase[P + p];
    for (int i = tid; i < ndst; i += 512)
        atomicAdd(&hd[ebuf_dst[base_d + i].x - node_lo], 1);
    __syncthreads();
    if (tid < nl) norm_src[node_lo + tid] = rsqrtf((float)max(hs[tid], 1));
    int myh = hd[tid];
    int incl = wave_incl_scan(myh);
    if ((tid & 63) == 63) wsum[wave] = incl;
    __syncthreads();
    if (tid == 0) {
        int a = 0;
#pragma unroll
        for (int i = 0; i < 8; ++i) { int t = wsum[i]; wsum[i] = a; a += t; }
    }
    __syncthreads();
    int row0 = base_d + incl - myh + wsum[wave];
    if (tid < nl) row_start[node_lo + tid] = row0;
    if (p == P - 1 && tid == 0) row_start[N] = E;
    __syncthreads();
    hd[tid] = row0;  // reuse as cursor
    __syncthreads();
    for (int i = tid; i < ndst; i += 512) {
        int2 r = ebuf_dst[base_d + i];
        int pos = atomicAdd(&hd[r.x - node_lo], 1);
        csr_src[pos] = r.y;
    }
}

// ---- MFMA GEMM: out[n x COLS](bf16) = A[n x 128] @ W[128 x COLS] --------
template <int COLS, bool BF16IN>
__launch_bounds__(256)
__global__ void gemm_mfma(const void* __restrict__ xin, const float* __restrict__ w,
                          const float* __restrict__ norm,
                          __hip_bfloat16* __restrict__ out, int n) {
    constexpr int NT = COLS / 16;
    __shared__ short wlds[4 * NT * 64 * 8];
    const int tid = threadIdx.x;
    for (int i = tid; i < 128 * COLS / 4; i += 256) {
        int k = (i * 4) / COLS;
        int n0 = (i * 4) % COLS;
        float4 wv = reinterpret_cast<const float4*>(w)[i];
        int c = k >> 5, q = (k >> 3) & 3, j = k & 7;
        float vals[4] = {wv.x, wv.y, wv.z, wv.w};
#pragma unroll
        for (int u = 0; u < 4; ++u) {
            int nn = n0 + u;
            int t = nn >> 4;
            int ln = (q << 4) | (nn & 15);
            union { __hip_bfloat16 b; short s; } cv;
            cv.b = __float2bfloat16(vals[u]);
            wlds[(((c * NT + t) << 6) | ln) * 8 + j] = cv.s;
        }
    }
    __syncthreads();

    const int lane = tid & 63;
    const int wid = tid >> 6;
    const int m = lane & 15;
    const int q = lane >> 4;
    const int ntiles = (n + 15) >> 4;
    const frag8* wfr = reinterpret_cast<const frag8*>(wlds);

    for (int wt = blockIdx.x * 4 + wid; wt < ntiles; wt += gridDim.x * 4) {
        const int row = (wt << 4) + m;
        frag8 af[4];
        if (row < n) {
            if constexpr (BF16IN) {
                const frag8* xp = reinterpret_cast<const frag8*>(
                    (const __hip_bfloat16*)xin + (size_t)row * 128);
#pragma unroll
                for (int c = 0; c < 4; ++c) af[c] = xp[c * 4 + q];
            } else {
                const float* xp = (const float*)xin + (size_t)row * 128;
                float nm = norm[row];
#pragma unroll
                for (int c = 0; c < 4; ++c) {
                    int base = c * 32 + q * 8;
                    float4 v0 = *reinterpret_cast<const float4*>(xp + base);
                    float4 v1 = *reinterpret_cast<const float4*>(xp + base + 4);
                    union { frag8 f; short s[8]; } a;
                    union { __hip_bfloat16 b; short s; } cv;
                    cv.b = __float2bfloat16(v0.x * nm); a.s[0] = cv.s;
                    cv.b = __float2bfloat16(v0.y * nm); a.s[1] = cv.s;
                    cv.b = __float2bfloat16(v0.z * nm); a.s[2] = cv.s;
                    cv.b = __float2bfloat16(v0.w * nm); a.s[3] = cv.s;
                    cv.b = __float2bfloat16(v1.x * nm); a.s[4] = cv.s;
                    cv.b = __float2bfloat16(v1.y * nm); a.s[5] = cv.s;
                    cv.b = __float2bfloat16(v1.z * nm); a.s[6] = cv.s;
                    cv.b = __float2bfloat16(v1.w * nm); a.s[7] = cv.s;
                    af[c] = a.f;
                }
            }
        } else {
#pragma unroll
            for (int c = 0; c < 4; ++c) af[c] = frag8{0, 0, 0, 0, 0, 0, 0, 0};
        }
        f32x4 acc[NT] = {};
#pragma unroll
        for (int c = 0; c < 4; ++c)
#pragma unroll
            for (int t = 0; t < NT; ++t)
                acc[t] = __builtin_amdgcn_mfma_f32_16x16x32_bf16(
                    af[c], wfr[(c * NT + t) * 64 + lane], acc[t], 0, 0, 0);
#pragma unroll
        for (int r = 0; r < 4; ++r) {
            int grow = (wt << 4) + q * 4 + r;
            if (grow < n) {
#pragma unroll
                for (int t = 0; t < NT; ++t)
                    out[(size_t)grow * COLS + t * 16 + m] = __float2bfloat16(acc[t][r]);
            }
        }
    }
}

// ---- SpMM layer 1: wave/node, pair-of-rows uint2 gathers, shfl combine --
__launch_bounds__(256)
__global__ void spmm1_kernel(const __hip_bfloat16* __restrict__ h,
                             const int* __restrict__ row_start,
                             const int* __restrict__ csr_src,
                             const float* __restrict__ b1,
                             const float* __restrict__ norm_src,
                             uint* __restrict__ out, int n) {
    int gw = (blockIdx.x * 256 + threadIdx.x) >> 6;
    if (gw >= n) return;
    int lane = threadIdx.x & 63;
    int hh = lane >> 5;   // which row of the pair
    int r = lane & 31;    // uint2 index within row (covers feats 4r..4r+3)
    int e0 = row_start[gw];
    int e1 = row_start[gw + 1];
    const uint2* hp = reinterpret_cast<const uint2*>(h);  // 32 uint2 per row
    float a0 = 0.f, a1 = 0.f, a2 = 0.f, a3 = 0.f;
    int e = e0;
    for (; e + 16 <= e1; e += 16) {
        uint2 v[8];
#pragma unroll
        for (int j = 0; j < 8; ++j)
            v[j] = hp[(size_t)csr_src[e + 2 * j + hh] * 32 + r];
#pragma unroll
        for (int j = 0; j < 8; ++j) {
            a0 += __uint_as_float(v[j].x << 16);
            a1 += __uint_as_float(v[j].x & 0xffff0000u);
            a2 += __uint_as_float(v[j].y << 16);
            a3 += __uint_as_float(v[j].y & 0xffff0000u);
        }
    }
    {   // predicated tail (up to 15 edges), loads kept independent
        uint2 v[8];
#pragma unroll
        for (int j = 0; j < 8; ++j) {
            v[j] = make_uint2(0u, 0u);
            int idx = e + 2 * j + hh;
            if (idx < e1) v[j] = hp[(size_t)csr_src[idx] * 32 + r];
        }
#pragma unroll
        for (int j = 0; j < 8; ++j) {
            a0 += __uint_as_float(v[j].x << 16);
            a1 += __uint_as_float(v[j].x & 0xffff0000u);
            a2 += __uint_as_float(v[j].y << 16);
            a3 += __uint_as_float(v[j].y & 0xffff0000u);
        }
    }
    a0 += __shfl_xor(a0, 32);
    a1 += __shfl_xor(a1, 32);
    a2 += __shfl_xor(a2, 32);
    a3 += __shfl_xor(a3, 32);
    if (hh == 0) {
        float nd = rsqrtf((float)max(e1 - e0, 1));
        float ns = norm_src[gw];
        float4 bb = reinterpret_cast<const float4*>(b1)[r];
        float o0 = fmaxf(fmaf(a0, nd, bb.x), 0.f) * ns;
        float o1 = fmaxf(fmaf(a1, nd, bb.y), 0.f) * ns;
        float o2 = fmaxf(fmaf(a2, nd, bb.z), 0.f) * ns;
        float o3 = fmaxf(fmaf(a3, nd, bb.w), 0.f) * ns;
        union { __hip_bfloat16 b; ushort s; } c0, c1, c2, c3;
        c0.b = __float2bfloat16(o0);
        c1.b = __float2bfloat16(o1);
        c2.b = __float2bfloat16(o2);
        c3.b = __float2bfloat16(o3);
        uint lo = (uint)c0.s | ((uint)c1.s << 16);
        uint hi = (uint)c2.s | ((uint)c3.s << 16);
        reinterpret_cast<uint2*>(out + (size_t)gw * 64)[r] = make_uint2(lo, hi);
    }
}

// ---- SpMM layer 2: wave/node, pair-of-rows uint gathers; emits bf16 y ---
__launch_bounds__(256)
__global__ void spmm2_kernel(const __hip_bfloat16* __restrict__ h,
                             const int* __restrict__ row_start,
                             const int* __restrict__ csr_src,
                             const float* __restrict__ b2, ushort* __restrict__ y, int n) {
    int gw = (blockIdx.x * 256 + threadIdx.x) >> 6;
    if (gw >= n) return;
    int lane = threadIdx.x & 63;
    int hh = lane >> 5;
    int r = lane & 31;    // uint index within row (covers feats 2r, 2r+1)
    int e0 = row_start[gw];
    int e1 = row_start[gw + 1];
    const uint* hp = reinterpret_cast<const uint*>(h);    // 32 uints per row
    float a0 = 0.f, a1 = 0.f;
    int e = e0;
    for (; e + 16 <= e1; e += 16) {
        uint v[8];
#pragma unroll
        for (int j = 0; j < 8; ++j)
            v[j] = hp[(size_t)csr_src[e + 2 * j + hh] * 32 + r];
#pragma unroll
        for (int j = 0; j < 8; ++j) {
            a0 += __uint_as_float(v[j] << 16);
            a1 += __uint_as_float(v[j] & 0xffff0000u);
        }
    }
    {
        uint v[8];
#pragma unroll
        for (int j = 0; j < 8; ++j) {
            v[j] = 0u;
            int idx = e + 2 * j + hh;
            if (idx < e1) v[j] = hp[(size_t)csr_src[idx] * 32 + r];
        }
#pragma unroll
        for (int j = 0; j < 8; ++j) {
            a0 += __uint_as_float(v[j] << 16);
            a1 += __uint_as_float(v[j] & 0xffff0000u);
        }
    }
    a0 += __shfl_xor(a0, 32);
    a1 += __shfl_xor(a1, 32);
    if (hh == 0) {
        float nd = rsqrtf((float)max(e1 - e0, 1));
        float2 bb = reinterpret_cast<const float2*>(b2)[r];
        float o0 = fmaxf(fmaf(a0, nd, bb.x), 0.f);
        float o1 = fmaxf(fmaf(a1, nd, bb.y), 0.f);
        union { __hip_bfloat16 b; ushort s; } c0, c1;
        c0.b = __float2bfloat16(o0);
        c1.b = __float2bfloat16(o1);
        reinterpret_cast<uint*>(y + (size_t)gw * 64)[r] =
            (uint)c0.s | ((uint)c1.s << 16);
    }
}

// ---- Fused pooling: one block per graph, binary-search bounds, divide ---
__launch_bounds__(256)
__global__ void pool_kernel(const ushort* __restrict__ y, const int* __restrict__ gids,
                            float* __restrict__ out, int n) {
    int g = blockIdx.x;
    int lo = 0, hi = n;
    while (lo < hi) {
        int mid = (lo + hi) >> 1;
        if (gids[mid] < g) lo = mid + 1; else hi = mid;
    }
    int s = lo;
    hi = n;
    while (lo < hi) {
        int mid = (lo + hi) >> 1;
        if (gids[mid] < g + 1) lo = mid + 1; else hi = mid;
    }
    int e = lo;
    int lane = threadIdx.x & 63;
    int wave = threadIdx.x >> 6;
    float acc = 0.f;
    int i = s + wave;
    for (; i + 12 < e; i += 16) {
        uint u0 = y[(size_t)(i + 0) * 64 + lane];
        uint u1 = y[(size_t)(i + 4) * 64 + lane];
        uint u2 = y[(size_t)(i + 8) * 64 + lane];
        uint u3 = y[(size_t)(i + 12) * 64 + lane];
        acc += __uint_as_float(u0 << 16) + __uint_as_float(u1 << 16) +
               __uint_as_float(u2 << 16) + __uint_as_float(u3 << 16);
    }
    for (; i < e; i += 4)
        acc += __uint_as_float((uint)y[(size_t)i * 64 + lane] << 16);
    __shared__ float sbuf[4][64];
    sbuf[wave][lane] = acc;
    __syncthreads();
    if (wave == 0) {
        float v = sbuf[0][lane] + sbuf[1][lane] + sbuf[2][lane] + sbuf[3][lane];
        out[(size_t)g * 64 + lane] = v / fmaxf((float)(e - s), 1.f);
    }
}

extern "C" void kernel_launch(void* const* d_in, const int* in_sizes, int n_in,
                              void* d_out, int out_size, void* d_ws, size_t ws_size,
                              hipStream_t stream) {
    const float* features = (const float*)d_in[0];
    const float* W1 = (const float*)d_in[1];
    const float* b1 = (const float*)d_in[2];
    const float* W2 = (const float*)d_in[3];
    const float* b2 = (const float*)d_in[4];
    const int* src = (const int*)d_in[5];
    const int* dst = (const int*)d_in[6];
    const int* gids = (const int*)d_in[7];
    const int N = in_sizes[7];
    const int E = in_sizes[5];
    const int G = out_size / 64;
    float* out = (float*)d_out;
    const int P = (N + NPP - 1) >> NPP_SHIFT;

    char* ws = (char*)d_ws;
    size_t off = 0;
    auto alloc = [&](size_t bytes) -> void* {
        void* p = ws + off;
        off = (off + bytes + 255) & ~(size_t)255;
        return p;
    };
    int* counts = (int*)alloc((size_t)2 * NB * P * 4);
    int* offs = (int*)alloc((size_t)2 * NB * P * 4);
    int* ptot = (int*)alloc((size_t)2 * P * 4);
    int* pbase = (int*)alloc((size_t)2 * P * 4);
    int* ebuf_src = (int*)alloc((size_t)E * 4);
    int2* ebuf_dst = (int2*)alloc((size_t)E * 8);
    float* norm_src = (float*)alloc((size_t)N * 4);
    int* row_start = (int*)alloc((size_t)(N + 1) * 4);
    int* csr_src = (int*)alloc((size_t)E * 4);
    __hip_bfloat16* h1 = (__hip_bfloat16*)alloc((size_t)N * 128 * 2);   // reused as h2
    __hip_bfloat16* x2n = (__hip_bfloat16*)alloc((size_t)N * 128 * 2);  // bf16, pre-normed
    ushort* y = (ushort*)alloc((size_t)N * 64 * 2);                     // bf16
    __hip_bfloat16* h2 = h1;  // h1 dead after spmm1

    // --- atomic-free graph build ---
    passA_count<<<NB, 256, 0, stream>>>(src, dst, E, P, counts, counts + (size_t)NB * P);
    scanB<<<2 * P, 512, 0, stream>>>(counts, offs, ptot, P);
    passC_scatter<<<NB, 256, 0, stream>>>(src, dst, E, P, offs, ptot, pbase,
                                          ebuf_src, ebuf_dst);
    passD_build<<<P, 512, 0, stream>>>(ebuf_src, ebuf_dst, ptot, pbase, norm_src, row_start,
                                       csr_src, N, E, P);

    // Layer 1: h1 = (features * norm_src) @ W1   (bf16 MFMA)
    gemm_mfma<128, false><<<768, 256, 0, stream>>>(features, W1, norm_src, h1, N);
    int spmm_blocks = (N + 3) / 4;  // 1 wave per node, 4 waves per block
    spmm1_kernel<<<spmm_blocks, 256, 0, stream>>>(h1, row_start, csr_src, b1, norm_src,
                                                  (uint*)x2n, N);
    // Layer 2: h2 = x2n @ W2   (x2n already includes norm_src)
    gemm_mfma<64, true><<<768, 256, 0, stream>>>(x2n, W2, nullptr, h2, N);
    spmm2_kernel<<<spmm_blocks, 256, 0, stream>>>(h2, row_start, csr_src, b2, y, N);
    // Per-graph mean (one block per graph; sorted gids)
    pool_kernel<<<G, 256, 0, stream>>>(y, gids, out, N);
}